// Round 9
// baseline (4301.361 us; speedup 1.0000x reference)
//
#include <hip/hip_runtime.h>

#define NU 500000
#define NI 200000
#define NN (NU + NI)
#define NE 2000000
#define HD 32
#define DF 256
#define OC 96

typedef float        f4  __attribute__((ext_vector_type(4)));
typedef unsigned int u2  __attribute__((ext_vector_type(2)));
typedef unsigned int u4v __attribute__((ext_vector_type(4)));
typedef short        s8v __attribute__((ext_vector_type(8)));
typedef unsigned short ushort_t;

__device__ __forceinline__ float lrelu(float v){ return v >= 0.f ? v : 0.01f*v; }

__device__ __forceinline__ unsigned int f2bf(float f){
  unsigned int u = __float_as_uint(f);
  u += 0x7fffu + ((u >> 16) & 1u);
  return u >> 16;
}
__device__ __forceinline__ float bflo(unsigned int u){ return __uint_as_float(u << 16); }
__device__ __forceinline__ float bfhi(unsigned int u){ return __uint_as_float(u & 0xffff0000u); }

__device__ __forceinline__ s8v pack8(f4 a, f4 b){
  s8v r;
  r[0]=(short)f2bf(a.x); r[1]=(short)f2bf(a.y); r[2]=(short)f2bf(a.z); r[3]=(short)f2bf(a.w);
  r[4]=(short)f2bf(b.x); r[5]=(short)f2bf(b.y); r[6]=(short)f2bf(b.z); r[7]=(short)f2bf(b.w);
  return r;
}

// degree histogram (users 0..NU-1, items NU..NN-1); cnt pre-zeroed by k_zero
__global__ void k_zero_i32(int* __restrict__ p, int n){
  int i = blockIdx.x*blockDim.x + threadIdx.x;
  if (i < n) p[i] = 0;
}

__global__ void k_deg(const int* __restrict__ esrc, const int* __restrict__ edst,
                      int* __restrict__ cnt){
  int e = blockIdx.x*blockDim.x + threadIdx.x;
  if (e >= NE) return;
  int u = __builtin_nontemporal_load(esrc + e);
  int p = __builtin_nontemporal_load(edst + e);
  atomicAdd(cnt + u, 1);
  atomicAdd(cnt + NU + p, 1);
}

// out row: col 0:32 = user_emb[ids], cols 32:96 = 0 (atomic accumulators); + bf16 table
__global__ void k_init_user(const int* __restrict__ ids, const float* __restrict__ emb,
                            float* __restrict__ outu, ushort_t* __restrict__ tbl){
  int i = blockIdx.x*blockDim.x + threadIdx.x;
  if (i >= NU) return;
  int uid = ids[i];
  const f4* s = (const f4*)(emb + (size_t)uid*HD);
  f4* d = (f4*)(outu + (size_t)i*OC);
  unsigned int pk[16];
  #pragma unroll
  for (int q = 0; q < 8; ++q) {
    f4 v = s[q];
    __builtin_nontemporal_store(v, d + q);
    pk[2*q]   = f2bf(v.x) | (f2bf(v.y) << 16);
    pk[2*q+1] = f2bf(v.z) | (f2bf(v.w) << 16);
  }
  f4 z = {0,0,0,0};
  #pragma unroll
  for (int q = 8; q < 24; ++q) __builtin_nontemporal_store(z, d + q);
  u4v* t = (u4v*)(tbl + (size_t)i*HD);
  #pragma unroll
  for (int q = 0; q < 4; ++q) {
    u4v v; v.x = pk[4*q]; v.y = pk[4*q+1]; v.z = pk[4*q+2]; v.w = pk[4*q+3];
    t[q] = v;
  }
}

// MFMA thin GEMM (R7-verified): outi[:,0:32] = feat @ W^T + b + iemb[ids];
// epilogue also zeroes cols 32:96 and writes the bf16 xp table.
__global__ __launch_bounds__(256) void k_init_item_mfma(
    const int* __restrict__ ids, const float* __restrict__ emb,
    const float* __restrict__ feat, const float* __restrict__ W,
    const float* __restrict__ bias, float* __restrict__ outi,
    ushort_t* __restrict__ tbl){
  int wave = threadIdx.x >> 6;
  int lane = threadIdx.x & 63;
  int tile = blockIdx.x*4 + wave;
  int row0 = tile*16;
  if (row0 >= NI) return;
  int m = lane & 15, grp = lane >> 4;

  s8v bfrag[16];
  #pragma unroll
  for (int ks = 0; ks < 8; ++ks) {
    #pragma unroll
    for (int nh = 0; nh < 2; ++nh) {
      const float* wp = W + (size_t)(nh*16 + m)*DF + ks*32 + grp*8;
      f4 w0 = *(const f4*)wp;
      f4 w1 = *(const f4*)(wp + 4);
      bfrag[ks*2 + nh] = pack8(w0, w1);
    }
  }

  f4 acc0 = {0,0,0,0}, acc1 = {0,0,0,0};
  const float* fr = feat + (size_t)(row0 + m)*DF + grp*8;
  #pragma unroll
  for (int ks = 0; ks < 8; ++ks) {
    f4 a0 = *(const f4*)(fr + ks*32);
    f4 a1 = *(const f4*)(fr + ks*32 + 4);
    s8v af = pack8(a0, a1);
    acc0 = __builtin_amdgcn_mfma_f32_16x16x32_bf16(af, bfrag[ks*2+0], acc0, 0, 0, 0);
    acc1 = __builtin_amdgcn_mfma_f32_16x16x32_bf16(af, bfrag[ks*2+1], acc1, 0, 0, 0);
  }

  f4 z = {0,0,0,0};
  #pragma unroll
  for (int j = 0; j < 4; ++j) {
    int r = row0 + grp*4 + j;
    int pid = ids[r];
    float v0 = acc0[j] + emb[(size_t)pid*HD + m]      + bias[m];
    float v1 = acc1[j] + emb[(size_t)pid*HD + 16 + m] + bias[16 + m];
    outi[(size_t)r*OC + m]      = v0;
    outi[(size_t)r*OC + 16 + m] = v1;
    // zero accumulator cols 32:96 (16 lanes x 16 B = 256 B)
    __builtin_nontemporal_store(z, (f4*)(outi + (size_t)r*OC + 32 + 4*m));
    // bf16 xp table
    tbl[(size_t)r*HD + m]      = (ushort_t)f2bf(v0);
    tbl[(size_t)r*HD + 16 + m] = (ushort_t)f2bf(v1);
  }
}

// edge-parallel push (R1-proven family): 8 lanes/edge, gather 8 B from dense bf16
// table (L3-resident), 4 independent f32 atomics into dst row's acc column.
__global__ void k_push(const ushort_t* __restrict__ tbl,
                       const int* __restrict__ eS, const int* __restrict__ eD,
                       float* __restrict__ outbase, int accoff){
  int tid = blockIdx.x*256 + threadIdx.x;
  int e = tid >> 3;
  if (e >= NE) return;
  int q = tid & 7;
  int s = eS[e];
  int d = eD[e];
  u2 v = ((const u2*)tbl)[(size_t)s*8 + q];
  float* a = outbase + (size_t)d*OC + accoff + q*4;
  atomicAdd(a + 0, bflo(v.x));
  atomicAdd(a + 1, bfhi(v.x));
  atomicAdd(a + 2, bflo(v.y));
  atomicAdd(a + 3, bfhi(v.y));
}

// in-place fin (R1-proven): row[accoff:+32] = lrelu((row[accoff:]/max(deg,1))@Wl^T
//                                                  + bl + row[xoff:]@Wr^T); + bf16 table
__global__ void k_fin(float* __restrict__ base, int n, int accoff, int xoff,
                      const int* __restrict__ cnt,
                      const float* __restrict__ Wl, const float* __restrict__ bl,
                      const float* __restrict__ Wr, ushort_t* __restrict__ tblout){
  int i = blockIdx.x*blockDim.x + threadIdx.x;
  if (i >= n) return;
  float* row = base + (size_t)i*OC;
  int c = cnt[i];
  float inv = (c > 0) ? 1.f/(float)c : 0.f;
  float m[HD], x[HD];
  #pragma unroll
  for (int q = 0; q < 8; ++q) {
    f4 a = *((const f4*)(row + accoff) + q);
    m[4*q+0]=a.x*inv; m[4*q+1]=a.y*inv; m[4*q+2]=a.z*inv; m[4*q+3]=a.w*inv;
    f4 xx = *((const f4*)(row + xoff) + q);
    x[4*q+0]=xx.x; x[4*q+1]=xx.y; x[4*q+2]=xx.z; x[4*q+3]=xx.w;
  }
  float y[HD];
  #pragma unroll
  for (int h = 0; h < HD; ++h) {
    float s = bl[h];
    #pragma unroll
    for (int j = 0; j < HD; ++j) s += m[j]*Wl[h*HD+j];   // W uniform -> s_load
    #pragma unroll
    for (int j = 0; j < HD; ++j) s += x[j]*Wr[h*HD+j];
    y[h] = lrelu(s);
  }
  #pragma unroll
  for (int q = 0; q < 8; ++q) {
    f4 yo; yo.x=y[4*q+0]; yo.y=y[4*q+1]; yo.z=y[4*q+2]; yo.w=y[4*q+3];
    *((f4*)(row + accoff) + q) = yo;     // in-place overwrite of acc col
  }
  if (tblout) {
    u4v pv[4];
    #pragma unroll
    for (int t = 0; t < 4; ++t) {
      pv[t].x = f2bf(y[8*t+0]) | (f2bf(y[8*t+1]) << 16);
      pv[t].y = f2bf(y[8*t+2]) | (f2bf(y[8*t+3]) << 16);
      pv[t].z = f2bf(y[8*t+4]) | (f2bf(y[8*t+5]) << 16);
      pv[t].w = f2bf(y[8*t+6]) | (f2bf(y[8*t+7]) << 16);
    }
    u4v* tb = (u4v*)(tblout + (size_t)i*HD);
    #pragma unroll
    for (int t = 0; t < 4; ++t) tb[t] = pv[t];
  }
}

extern "C" void kernel_launch(void* const* d_in, const int* in_sizes, int n_in,
                              void* d_out, int out_size, void* d_ws, size_t ws_size,
                              hipStream_t stream) {
  const int*   user_ids = (const int*)d_in[0];
  const int*   prod_ids = (const int*)d_in[1];
  const float* feat     = (const float*)d_in[2];
  const int*   er       = (const int*)d_in[3];   // [2, NE]: row0 = user, row1 = item
  const float* uemb     = (const float*)d_in[5];
  const float* iemb     = (const float*)d_in[6];
  const float* fW       = (const float*)d_in[7];
  const float* fb       = (const float*)d_in[8];
  const float* Wl_up1 = (const float*)d_in[9];
  const float* bl_up1 = (const float*)d_in[10];
  const float* Wr_up1 = (const float*)d_in[11];
  const float* Wl_pu1 = (const float*)d_in[12];
  const float* bl_pu1 = (const float*)d_in[13];
  const float* Wr_pu1 = (const float*)d_in[14];
  const float* Wl_up2 = (const float*)d_in[15];
  const float* bl_up2 = (const float*)d_in[16];
  const float* Wr_up2 = (const float*)d_in[17];
  const float* Wl_pu2 = (const float*)d_in[18];
  const float* bl_pu2 = (const float*)d_in[19];
  const float* Wr_pu2 = (const float*)d_in[20];

  float* outu = (float*)d_out;
  float* outi = outu + (size_t)NU*OC;

  // ws: cnt[NN] i32 | tblU | tblI | tblU2 | tblI2   (bf16 rows of 64 B) = ~92 MB
  char* w = (char*)d_ws;
  int* cnt = (int*)w;              w += ((size_t)NN*4 + 255) & ~(size_t)255;
  ushort_t* tblU  = (ushort_t*)w;  w += (size_t)NU*HD*2;
  ushort_t* tblI  = (ushort_t*)w;  w += (size_t)NI*HD*2;
  ushort_t* tblU2 = (ushort_t*)w;  w += (size_t)NU*HD*2;
  ushort_t* tblI2 = (ushort_t*)w;

  const int* er_src = er;        // users
  const int* er_dst = er + NE;   // items

  const int B = 256;
  const int GE  = (NE + B - 1)/B;
  const int GE8 = (int)(((size_t)NE*8 + B - 1)/B);
  const int GU1 = (NU + B - 1)/B, GI1 = (NI + B - 1)/B;

  k_zero_i32<<<(NN + B - 1)/B, B, 0, stream>>>(cnt, NN);
  k_deg<<<GE, B, 0, stream>>>(er_src, er_dst, cnt);

  k_init_user<<<GU1, B, 0, stream>>>(user_ids, uemb, outu, tblU);
  k_init_item_mfma<<<(NI + 63)/64, 256, 0, stream>>>(prod_ids, iemb, feat, fW, fb,
                                                     outi, tblI);

  // s1a: items <- users (xu); acc/out in outi cols 32:64
  k_push<<<GE8, B, 0, stream>>>(tblU, er_src, er_dst, outi, 32);
  k_fin<<<GI1, B, 0, stream>>>(outi, NI, 32, 0, cnt + NU, Wl_up1, bl_up1, Wr_up1, tblI2);
  // s1b: users <- items (xp); outu cols 32:64
  k_push<<<GE8, B, 0, stream>>>(tblI, er_dst, er_src, outu, 32);
  k_fin<<<GU1, B, 0, stream>>>(outu, NU, 32, 0, cnt, Wl_pu1, bl_pu1, Wr_pu1, tblU2);
  // s2a: items <- u1; outi cols 64:96
  k_push<<<GE8, B, 0, stream>>>(tblU2, er_src, er_dst, outi, 64);
  k_fin<<<GI1, B, 0, stream>>>(outi, NI, 64, 32, cnt + NU, Wl_up2, bl_up2, Wr_up2,
                               (ushort_t*)nullptr);
  // s2b: users <- p1; outu cols 64:96
  k_push<<<GE8, B, 0, stream>>>(tblI2, er_dst, er_src, outu, 64);
  k_fin<<<GU1, B, 0, stream>>>(outu, NU, 64, 32, cnt, Wl_pu2, bl_pu2, Wr_pu2,
                               (ushort_t*)nullptr);
}